// Round 5
// baseline (230.309 us; speedup 1.0000x reference)
//
#include <hip/hip_runtime.h>

#define NN 50000
#define EE 1600000
#define CC 128
#define HH 8
#define TOT (EE + NN)               // 1,650,000 output rows
#define RPB 256                     // rows per bucket
#define NB  ((NN + RPB - 1) / RPB)  // 196 buckets
#define BCH 4096                    // edges per binning block
#define NBB ((EE + BCH - 1) / BCH)  // 391 binning blocks
#define MST 9                       // padded LDS stride (gcd(9,32)=1)

// ---- monotone float<->uint mapping for atomic max on floats ----
__device__ inline unsigned fflip(float f) {
    unsigned u = __float_as_uint(f);
    return (u & 0x80000000u) ? ~u : (u | 0x80000000u);
}
__device__ inline float funflip(unsigned u) {
    unsigned b = (u & 0x80000000u) ? (u ^ 0x80000000u) : ~u;
    return __uint_as_float(b);
}

// leaky_relu(z,0.2)*100
__device__ inline float act(float z) {
    z = (z >= 0.f) ? z : 0.2f * z;
    return z * 100.f;
}

// ---- y1b = x @ W[:C] + b, y2 = x @ W[C:]  (N x 8 each) ----
__global__ __launch_bounds__(256) void k_proj(const float* __restrict__ x,
                                              const float* __restrict__ W,
                                              const float* __restrict__ bias,
                                              float* __restrict__ y1b,
                                              float* __restrict__ y2) {
    __shared__ float w[2 * CC * HH];  // 2048 floats
    int tid = threadIdx.x;
    for (int i = tid; i < 2 * CC * HH; i += 256) w[i] = W[i];
    __syncthreads();
    int node = blockIdx.x * 16 + (tid >> 4);
    int j = tid & 15;
    if (node >= NN) return;
    int wofs = (j < 8) ? j : (CC * HH + j - 8);
    const float4* xv = (const float4*)(x + (size_t)node * CC);
    float acc = 0.f;
#pragma unroll 4
    for (int k4 = 0; k4 < CC / 4; ++k4) {
        float4 xx = xv[k4];
        int base = k4 * 32 + wofs;
        acc += xx.x * w[base];
        acc += xx.y * w[base + 8];
        acc += xx.z * w[base + 16];
        acc += xx.w * w[base + 24];
    }
    if (j < 8) y1b[(size_t)node * 8 + j] = acc + bias[j];
    else       y2[(size_t)node * 8 + (j - 8)] = acc;
}

// ---- bucket histogram: LDS-aggregated ----
__global__ __launch_bounds__(1024) void k_hist(const int* __restrict__ rowp,
                                               int* __restrict__ gcnt) {
    __shared__ int h[NB];
    int t = threadIdx.x;
    for (int i = t; i < NB; i += 1024) h[i] = 0;
    __syncthreads();
    int base = blockIdx.x * BCH;
    int n = EE - base; if (n > BCH) n = BCH;
    for (int i = t; i < n; i += 1024)
        atomicAdd(&h[rowp[base + i] >> 8], 1);
    __syncthreads();
    for (int i = t; i < NB; i += 1024)
        if (h[i]) atomicAdd(&gcnt[i], h[i]);
}

// ---- scan of NB bucket counts -> gbase[NB+1], gcur copy ----
__global__ __launch_bounds__(256) void k_scanb(const int* __restrict__ gcnt,
                                               int* __restrict__ gbase,
                                               int* __restrict__ gcur) {
    __shared__ int p[256];
    int t = threadIdx.x;
    int own = (t < NB) ? gcnt[t] : 0;
    p[t] = own;
    __syncthreads();
    for (int off = 1; off < 256; off <<= 1) {
        int v = (t >= off) ? p[t - off] : 0;
        __syncthreads();
        p[t] += v;
        __syncthreads();
    }
    if (t < NB) {
        int ex = p[t] - own;
        gbase[t] = ex;
        gcur[t] = ex;
    }
    if (t == NB - 1) gbase[NB] = p[t];
}

// ---- binning: pack payload (rloc|col<<8|bkt<<24, |ea|), coalesced flush ----
__global__ __launch_bounds__(1024) void k_bin(const int* __restrict__ rowp,
                                              const int* __restrict__ colp,
                                              const float* __restrict__ ea,
                                              int* __restrict__ gcur,
                                              uint2* __restrict__ pay) {
    __shared__ int hist[NB];
    __shared__ int lscan[NB];
    __shared__ int lofs[NB];
    __shared__ int gofs[NB];
    __shared__ int sc[256];
    __shared__ uint2 stage[BCH];   // 32 KB
    int t = threadIdx.x;
    int base = blockIdx.x * BCH;
    int n = EE - base; if (n > BCH) n = BCH;
    for (int i = t; i < NB; i += 1024) hist[i] = 0;
    __syncthreads();
    for (int i = t; i < n; i += 1024)
        atomicAdd(&hist[rowp[base + i] >> 8], 1);
    __syncthreads();
    int own = 0;
    if (t < 256) { own = (t < NB) ? hist[t] : 0; sc[t] = own; }
    __syncthreads();
    for (int off = 1; off < 256; off <<= 1) {
        int v = 0;
        if (t < 256 && t >= off) v = sc[t - off];
        __syncthreads();
        if (t < 256 && t >= off) sc[t] += v;
        __syncthreads();
    }
    if (t < NB) {
        int ex = sc[t] - own;
        lscan[t] = ex;
        lofs[t] = ex;
        gofs[t] = own ? atomicAdd(&gcur[t], own) : 0;
    }
    __syncthreads();
    // place packed payload into stage, grouped by bucket
    for (int i = t; i < n; i += 1024) {
        int r = rowp[base + i];
        int c = colp[base + i];
        float w = fabsf(ea[base + i]);
        int bkt = r >> 8;
        int p = atomicAdd(&lofs[bkt], 1);
        stage[p] = make_uint2((unsigned)(r & 0xFF) | ((unsigned)c << 8) |
                              ((unsigned)bkt << 24),
                              __float_as_uint(w));
    }
    __syncthreads();
    // flush: consecutive staged slots of a bucket -> consecutive global slots
    for (int i = t; i < n; i += 1024) {
        uint2 v = stage[i];
        int bkt = v.x >> 24;
        pay[gofs[bkt] + (i - lscan[bkt])] = v;
    }
}

// ---- per-bucket segment max+sum: 8 lanes per edge (h = lane&7) ----
__global__ __launch_bounds__(1024) void k_ms(const int* __restrict__ gbase,
                                             const uint2* __restrict__ pay,
                                             const float* __restrict__ y1b,
                                             const float* __restrict__ y2,
                                             float2* __restrict__ ms) {
    __shared__ unsigned mloc[RPB * MST];  // 9.2 KB
    __shared__ float    sloc[RPB * MST];  // 9.2 KB
    __shared__ float    yloc[RPB * MST];  // 9.2 KB (y1b rows, padded)
    int b = blockIdx.x;
    int r0 = b * RPB;
    int nr = NN - r0; if (nr > RPB) nr = RPB;
    int t = threadIdx.x;
    // init with self-loop alpha (always present -> no -inf handling)
    for (int i = t; i < nr * HH; i += 1024) {
        int rr = i >> 3, h = i & 7;
        float yv = y1b[(size_t)r0 * 8 + i];
        float a = act(yv + y2[(size_t)r0 * 8 + i]);   // self: c == r
        int idx = rr * MST + h;
        yloc[idx] = yv;
        mloc[idx] = fflip(a);
        sloc[idx] = a;                                // stash self alpha
    }
    __syncthreads();
    int s0 = gbase[b], s1 = gbase[b + 1];
    int h = t & 7;
    int eo = t >> 3;            // 0..127
    // sweep a: max (8 lanes per edge; y2 read is 32B-coalesced per edge)
    for (int i = s0 + eo; i < s1; i += 128) {
        uint2 p = pay[i];
        int rloc = p.x & 0xFF;
        int c = (p.x >> 8) & 0xFFFF;
        float w = __uint_as_float(p.y);
        float vb = y2[(size_t)c * 8 + h];
        int idx = rloc * MST + h;
        atomicMax(&mloc[idx], fflip(act((yloc[idx] + vb) * w)));
    }
    __syncthreads();
    // convert self stash -> s init = exp(a_self - m)
    for (int i = t; i < nr * HH; i += 1024) {
        int idx = (i >> 3) * MST + (i & 7);
        sloc[idx] = __expf(sloc[idx] - funflip(mloc[idx]));
    }
    __syncthreads();
    // sweep b: sum of exp
    for (int i = s0 + eo; i < s1; i += 128) {
        uint2 p = pay[i];
        int rloc = p.x & 0xFF;
        int c = (p.x >> 8) & 0xFFFF;
        float w = __uint_as_float(p.y);
        float vb = y2[(size_t)c * 8 + h];
        int idx = rloc * MST + h;
        float a = act((yloc[idx] + vb) * w);
        atomicAdd(&sloc[idx], __expf(a - funflip(mloc[idx])));
    }
    __syncthreads();
    for (int i = t; i < nr * HH; i += 1024) {
        int idx = (i >> 3) * MST + (i & 7);
        ms[(size_t)r0 * 8 + i] = make_float2(funflip(mloc[idx]), sloc[idx]);
    }
}

// ---- finalize: 8 lanes per output row; all gathers group-coalesced ----
__global__ __launch_bounds__(256) void k_final(const int* __restrict__ rowp,
                                               const int* __restrict__ colp,
                                               const float* __restrict__ ea,
                                               const float* __restrict__ y1b,
                                               const float* __restrict__ y2,
                                               const float2* __restrict__ ms,
                                               float* __restrict__ alpha,
                                               float* __restrict__ oidx) {
    long long g = (long long)blockIdx.x * 256 + threadIdx.x;
    int e = (int)(g >> 3);
    int h = (int)(g & 7);
    if (e >= TOT) return;
    int r, c; float w;
    if (e < EE) { r = rowp[e]; c = colp[e]; w = fabsf(ea[e]); }
    else        { r = e - EE;  c = r;       w = 1.0f; }
    float a = act((y1b[(size_t)r * 8 + h] + y2[(size_t)c * 8 + h]) * w);
    float2 msv = ms[(size_t)r * 8 + h];
    alpha[(size_t)e * 8 + h] = __expf(a - msv.x) / (msv.y + 1e-16f);
    if (h == 0) oidx[e] = (float)r;
    if (h == 1) oidx[(size_t)TOT + e] = (float)c;
}

extern "C" void kernel_launch(void* const* d_in, const int* in_sizes, int n_in,
                              void* d_out, int out_size, void* d_ws, size_t ws_size,
                              hipStream_t stream) {
    const float* x    = (const float*)d_in[0];
    const int*   rowp = (const int*)d_in[1];          // edge_index[0]
    const int*   colp = rowp + EE;                    // edge_index[1]
    const float* ea   = (const float*)d_in[2];
    const float* W    = (const float*)d_in[3];
    const float* bias = (const float*)d_in[4];

    float* out_alpha = (float*)d_out;                 // [TOT][8]
    float* out_idx   = out_alpha + (size_t)TOT * 8;   // [2][TOT] as float

    // workspace layout
    float*  y1b   = (float*)d_ws;                     // NN*8
    float*  y2    = y1b + (size_t)NN * 8;             // NN*8
    float2* ms    = (float2*)(y2 + (size_t)NN * 8);   // NN*8 float2
    uint2*  pay   = (uint2*)(ms + (size_t)NN * 8);    // EE uint2 (12.8 MB)
    int*    gcnt  = (int*)(pay + (size_t)EE);         // NB
    int*    gbase = gcnt + NB;                        // NB+1
    int*    gcur  = gbase + NB + 1;                   // NB

    hipMemsetAsync(gcnt, 0, NB * sizeof(int), stream);
    k_proj<<<(NN * 16 + 255) / 256, 256, 0, stream>>>(x, W, bias, y1b, y2);
    k_hist<<<NBB, 1024, 0, stream>>>(rowp, gcnt);
    k_scanb<<<1, 256, 0, stream>>>(gcnt, gbase, gcur);
    k_bin<<<NBB, 1024, 0, stream>>>(rowp, colp, ea, gcur, pay);
    k_ms<<<NB, 1024, 0, stream>>>(gbase, pay, y1b, y2, ms);
    long long fin_threads = (long long)TOT * 8;
    int fin_blocks = (int)((fin_threads + 255) / 256);
    k_final<<<fin_blocks, 256, 0, stream>>>(rowp, colp, ea, y1b, y2, ms,
                                            out_alpha, out_idx);
}